// Round 5
// baseline (399.923 us; speedup 1.0000x reference)
//
#include <hip/hip_runtime.h>
#include <math.h>

typedef __attribute__((ext_vector_type(8)))  short          short8;
typedef __attribute__((ext_vector_type(8)))  unsigned short ushort8;
typedef __attribute__((ext_vector_type(8)))  _Float16       half8;
typedef __attribute__((ext_vector_type(16))) float          f32x16;

#define Bb 16
#define Cc 256
#define Tt 2048

// ---- workspace layout (bytes) ----
#define WH_OFF    0u                         // ushort [320][256] bf16-hi of W
#define WL_OFF    163840u                    // ushort [320][256] bf16-lo of W
#define BALL_OFF  327680u                    // fp32 [320]
#define QTF_OFF   328960u                    // ushort [16][2048][32] fp16 bits, [t][c]
#define KTF_OFF   (QTF_OFF + 2097152u)
#define VBF_OFF   (KTF_OFF + 2097152u)       // ushort [16][256][2048] bf16 bits, [c][t]

__device__ __forceinline__ unsigned short f2bf(float f) {
  union { float f; unsigned u; } v; v.f = f;
  unsigned r = v.u + 0x7fffu + ((v.u >> 16) & 1u);   // RNE
  return (unsigned short)(r >> 16);
}
__device__ __forceinline__ float bf2f(unsigned short h) {
  union { unsigned u; float f; } v; v.u = ((unsigned)h) << 16;
  return v.f;
}
__device__ __forceinline__ unsigned short f2h(float f) {
  union { _Float16 h; unsigned short u; } v; v.h = (_Float16)f;   // v_cvt_f16_f32
  return v.u;
}

// ---------------------------------------------------------------------------
// pack: W -> bf16 hi/lo planes [320][256] (+ bias fp32[320]).  (unchanged)
// ---------------------------------------------------------------------------
__global__ __launch_bounds__(256) void pack_kernel(
    const float* __restrict__ Wq, const float* __restrict__ bq,
    const float* __restrict__ Wk, const float* __restrict__ bk,
    const float* __restrict__ Wv, const float* __restrict__ bv,
    char* ws) {
  unsigned short* WH = (unsigned short*)(ws + WH_OFF);
  unsigned short* WL = (unsigned short*)(ws + WL_OFF);
  float* ball = (float*)(ws + BALL_OFF);
  int o = blockIdx.x, c = threadIdx.x;
  float v;
  if (o < 32)      v = Wq[o * 256 + c];
  else if (o < 64) v = Wk[(o - 32) * 256 + c];
  else             v = Wv[(o - 64) * 256 + c];
  unsigned short hb = f2bf(v);
  WH[o * 256 + c] = hb;
  WL[o * 256 + c] = f2bf(v - bf2f(hb));
  if (c == 0) ball[o] = (o < 32) ? bq[o] : (o < 64 ? bk[o - 32] : bv[o - 64]);
}

// ---------------------------------------------------------------------------
// proj (MFMA): same as round 3/4 except Q/K epilogue stores a single fp16
// plane ([b][t][32]) instead of bf16 hi/lo.
// ---------------------------------------------------------------------------
__global__ __launch_bounds__(256, 2) void proj_kernel(
    const float* __restrict__ x, char* ws) {
  __shared__ __align__(16) float xs[128 * 64];
  __shared__ __align__(16) unsigned short xth[64 * 136];
  __shared__ __align__(16) unsigned short xtl[64 * 136];

  const unsigned short* WH = (const unsigned short*)(ws + WH_OFF);
  const unsigned short* WL = (const unsigned short*)(ws + WL_OFF);
  const float* ball = (const float*)(ws + BALL_OFF);
  unsigned short* Qtf = (unsigned short*)(ws + QTF_OFF);
  unsigned short* Ktf = (unsigned short*)(ws + KTF_OFF);
  unsigned short* Vbf = (unsigned short*)(ws + VBF_OFF);

  const int b   = blockIdx.y;
  const int t0  = blockIdx.x * 64;
  const int tid = threadIdx.x;
  const int w    = tid >> 6;
  const int lane = tid & 63;
  const int m    = lane & 31;
  const int hh   = lane >> 5;

  const float* xb = x + ((size_t)b * 256) * 2048 + t0;

  f32x16 qkacc;
  f32x16 vacc[4];
  #pragma unroll
  for (int r = 0; r < 16; ++r) qkacc[r] = 0.f;
  #pragma unroll
  for (int j = 0; j < 4; ++j)
    #pragma unroll
    for (int r = 0; r < 16; ++r) vacc[j][r] = 0.f;

  #pragma unroll
  for (int r = 0; r < 8; ++r) {
    int idx = r * 256 + tid;
    int c = idx >> 4, f = idx & 15;
    *(float4*)&xs[c * 64 + 4 * f] = *(const float4*)&xb[(size_t)c * 2048 + 4 * f];
  }
  __syncthreads();

  const int tt = w & 1;
  const int qo = 32 * (w >> 1);

  #pragma unroll
  for (int half = 0; half < 2; ++half) {
    {
      const int t = lane;
      const int cq = w * 32;
      #pragma unroll
      for (int g = 0; g < 4; ++g) {
        ushort8 h8, l8;
        #pragma unroll
        for (int j = 0; j < 8; ++j) {
          float v = xs[(cq + g * 8 + j) * 64 + t];
          unsigned short hb = f2bf(v);
          h8[j] = hb;
          l8[j] = f2bf(v - bf2f(hb));
        }
        *(ushort8*)&xth[t * 136 + cq + g * 8] = h8;
        *(ushort8*)&xtl[t * 136 + cq + g * 8] = l8;
      }
    }
    __syncthreads();

    float4 pre[8];
    if (half == 0) {
      #pragma unroll
      for (int r = 0; r < 8; ++r) {
        int idx = r * 256 + tid;
        int c = idx >> 4, f = idx & 15;
        pre[r] = *(const float4*)&xb[(size_t)(128 + c) * 2048 + 4 * f];
      }
    }

    #pragma unroll
    for (int kk = 0; kk < 8; ++kk) {
      const int kl = kk * 16 + 8 * hh;
      const int kg = half * 128 + kl;
      short8 bh = *(const short8*)&xth[(32 * tt + m) * 136 + kl];
      short8 bl = *(const short8*)&xtl[(32 * tt + m) * 136 + kl];
      short8 ah = *(const short8*)&WH[(size_t)(qo + m) * 256 + kg];
      short8 al = *(const short8*)&WL[(size_t)(qo + m) * 256 + kg];
      qkacc = __builtin_amdgcn_mfma_f32_32x32x16_bf16(ah, bh, qkacc, 0, 0, 0);
      qkacc = __builtin_amdgcn_mfma_f32_32x32x16_bf16(ah, bl, qkacc, 0, 0, 0);
      qkacc = __builtin_amdgcn_mfma_f32_32x32x16_bf16(al, bh, qkacc, 0, 0, 0);
      #pragma unroll
      for (int j = 0; j < 4; ++j) {
        short8 av = *(const short8*)&WH[(size_t)(64 + 32 * (2 * j + (w >> 1)) + m) * 256 + kg];
        vacc[j] = __builtin_amdgcn_mfma_f32_32x32x16_bf16(av, bh, vacc[j], 0, 0, 0);
      }
    }

    if (half == 0) {
      #pragma unroll
      for (int r = 0; r < 8; ++r) {
        int idx = r * 256 + tid;
        int c = idx >> 4, f = idx & 15;
        *(float4*)&xs[c * 64 + 4 * f] = pre[r];
      }
      __syncthreads();
    }
  }

  // Q/K epilogue: single fp16 plane
  {
    unsigned short* pt = (w < 2) ? Qtf : Ktf;
    const int tcol = t0 + 32 * tt + m;
    #pragma unroll
    for (int r = 0; r < 16; ++r) {
      int orow = (r & 3) + 8 * (r >> 2) + 4 * hh;
      float v = qkacc[r] + ball[qo + orow];
      pt[((size_t)b * 2048 + tcol) * 32 + orow] = f2h(v);
    }
  }
  // V epilogue: bf16 [c][t]
  #pragma unroll
  for (int j = 0; j < 4; ++j) {
    const int vob = 64 + 32 * (2 * j + (w >> 1));
    #pragma unroll
    for (int r = 0; r < 16; ++r) {
      int orow = (r & 3) + 8 * (r >> 2) + 4 * hh;
      int o = vob + orow;
      float v = vacc[j][r] + ball[o];
      Vbf[((size_t)b * 256 + (o - 64)) * 2048 + t0 + 32 * tt + m] = f2h(0), // dummy no
      Vbf[((size_t)b * 256 + (o - 64)) * 2048 + t0 + 32 * tt + m] = f2bf(v);
    }
  }
}

// ---------------------------------------------------------------------------
// attn v3: fp16 Q/K frags straight from global (no LDS), QK = 2 f16 MFMAs,
// double-buffered Vs + depth-2 register prefetch, 2 barriers/iter,
// rotation-swizzled Vs/Ps (slot = (unit+row)&7, conflict-free per 8-lane phase).
// Wave w: QK tile (n=w>>1 q-tile, u=w&1 s-tile); PV c-tiles {w,w+4} x both q.
// ---------------------------------------------------------------------------
__global__ __launch_bounds__(256, 2) void attn_kernel(
    const float* __restrict__ x, const char* __restrict__ ws,
    float* __restrict__ out) {
  __shared__ __align__(16) unsigned short Vs[2][256 * 64];  // [c][s], rot-swizzled
  __shared__ __align__(16) unsigned short Ps[64 * 64];      // [q][s], rot-swizzled
  __shared__ float sums[64][2];
  __shared__ float invs[64];

  const unsigned short* Qt = (const unsigned short*)(ws + QTF_OFF);
  const unsigned short* Kt = (const unsigned short*)(ws + KTF_OFF);

  const int id = blockIdx.x;
  const int b  = ((id & 7) << 1) | ((id >> 3) & 1);   // 2 batches per XCD
  const int qt = id >> 4;
  const int t0 = qt * 64;
  const int tid  = threadIdx.x;
  const int w    = tid >> 6;
  const int lane = tid & 63;
  const int m    = lane & 31;
  const int hh   = lane >> 5;
  const int n    = w >> 1;
  const int u    = w & 1;

  const unsigned short* Vg =
      (const unsigned short*)(ws + VBF_OFF) + (size_t)b * 256 * 2048;
  const int vk = tid & 7, vc = tid >> 3;   // V staging: rows r*32+vc, unit vk

  // ---- persistent Q frags from global ----
  half8 qf[2];
  #pragma unroll
  for (int ks = 0; ks < 2; ++ks)
    qf[ks] = *(const half8*)&Qt[((size_t)b * 2048 + t0 + 32 * n + m) * 32 + 16 * ks + 8 * hh];

  // ---- K frag double buffer: prime tile 0 ----
  half8 kfb[2][2];
  #pragma unroll
  for (int ks = 0; ks < 2; ++ks)
    kfb[0][ks] = *(const half8*)&Kt[((size_t)b * 2048 + 32 * u + m) * 32 + 16 * ks + 8 * hh];

  // ---- V: tile 0 -> Vs[0]; vpre <- tile 1 ----
  ushort8 vpre[8];
  #pragma unroll
  for (int r = 0; r < 8; ++r) {
    int c = r * 32 + vc;
    ushort8 v0 = *(const ushort8*)&Vg[(size_t)c * 2048 + vk * 8];
    *(ushort8*)&Vs[0][c * 64 + (((vk + c) & 7) << 3)] = v0;
    vpre[r] = *(const ushort8*)&Vg[(size_t)c * 2048 + 64 + vk * 8];
  }
  __syncthreads();

  f32x16 pacc[2][2];
  #pragma unroll
  for (int a = 0; a < 2; ++a)
    #pragma unroll
    for (int d = 0; d < 2; ++d)
      #pragma unroll
      for (int r = 0; r < 16; ++r) pacc[a][d][r] = 0.f;
  float sacc[16];
  #pragma unroll
  for (int r = 0; r < 16; ++r) sacc[r] = 0.f;

  int p = 0;
  for (int it = 0; it < 32; ++it) {
    const int cur = it & 1;
    // prefetch next K frags (consumed next iter)
    if (it < 31) {
      const int sb2 = (it + 1) * 64;
      #pragma unroll
      for (int ks = 0; ks < 2; ++ks)
        kfb[cur ^ 1][ks] =
            *(const half8*)&Kt[((size_t)b * 2048 + sb2 + 32 * u + m) * 32 + 16 * ks + 8 * hh];
    }

    // ---- QK (2 f16 MFMAs) + exp -> Ps ----
    {
      f32x16 qacc;
      #pragma unroll
      for (int r = 0; r < 16; ++r) qacc[r] = 0.f;
      qacc = __builtin_amdgcn_mfma_f32_32x32x16_f16(qf[0], kfb[cur][0], qacc, 0, 0, 0);
      qacc = __builtin_amdgcn_mfma_f32_32x32x16_f16(qf[1], kfb[cur][1], qacc, 0, 0, 0);
      const int sc = 32 * u + m;
      const int scu = sc >> 3, sco = sc & 7;
      #pragma unroll
      for (int r = 0; r < 16; ++r) {
        float e = __expf(qacc[r]);
        unsigned short hb = f2bf(e);
        sacc[r] += bf2f(hb);
        int qq = 32 * n + (r & 3) + 8 * (r >> 2) + 4 * hh;
        Ps[qq * 64 + (((scu + qq) & 7) << 3) + sco] = hb;
      }
    }
    __syncthreads();

    // ---- PV phase: land vpre -> Vs[p^1], issue depth-2 V prefetch, 16 MFMAs ----
    if (it < 31) {
      #pragma unroll
      for (int r = 0; r < 8; ++r) {
        int c = r * 32 + vc;
        *(ushort8*)&Vs[p ^ 1][c * 64 + (((vk + c) & 7) << 3)] = vpre[r];
      }
    }
    if (it < 30) {
      const int sb3 = (it + 2) * 64;
      #pragma unroll
      for (int r = 0; r < 8; ++r) {
        int c = r * 32 + vc;
        vpre[r] = *(const ushort8*)&Vg[(size_t)c * 2048 + sb3 + vk * 8];
      }
    }
    #pragma unroll
    for (int ks = 0; ks < 4; ++ks) {
      const int uu = 2 * ks + hh;
      short8 p0 = *(const short8*)&Ps[m * 64 + (((uu + m) & 7) << 3)];
      short8 p1 = *(const short8*)&Ps[(32 + m) * 64 + (((uu + m) & 7) << 3)];
      int c0 = 32 * w + m, c1 = 32 * (w + 4) + m;
      short8 v0 = *(const short8*)&Vs[p][c0 * 64 + (((uu + c0) & 7) << 3)];
      short8 v1 = *(const short8*)&Vs[p][c1 * 64 + (((uu + c1) & 7) << 3)];
      pacc[0][0] = __builtin_amdgcn_mfma_f32_32x32x16_bf16(v0, p0, pacc[0][0], 0, 0, 0);
      pacc[0][1] = __builtin_amdgcn_mfma_f32_32x32x16_bf16(v1, p0, pacc[0][1], 0, 0, 0);
      pacc[1][0] = __builtin_amdgcn_mfma_f32_32x32x16_bf16(v0, p1, pacc[1][0], 0, 0, 0);
      pacc[1][1] = __builtin_amdgcn_mfma_f32_32x32x16_bf16(v1, p1, pacc[1][1], 0, 0, 0);
    }
    __syncthreads();
    p ^= 1;
  }

  // ---- row sums ----
  #pragma unroll
  for (int r = 0; r < 16; ++r) {
    float v = sacc[r];
    #pragma unroll
    for (int off = 1; off < 32; off <<= 1) v += __shfl_xor(v, off, 64);
    if (m == 0) sums[32 * n + (r & 3) + 8 * (r >> 2) + 4 * hh][u] = v;
  }
  __syncthreads();
  if (tid < 64) invs[tid] = 1.0f / (sums[tid][0] + sums[tid][1]);
  __syncthreads();

  // ---- epilogue: out = pacc/sum + x, coalesced along t (col = q) ----
  const float inv0 = invs[m], inv1 = invs[32 + m];
  #pragma unroll
  for (int nn = 0; nn < 2; ++nn) {
    const float inv = nn ? inv1 : inv0;
    const int q = 32 * nn + m;
    #pragma unroll
    for (int mi = 0; mi < 2; ++mi) {
      const int cbase = 32 * (w + 4 * mi);
      #pragma unroll
      for (int r = 0; r < 16; ++r) {
        int c = cbase + (r & 3) + 8 * (r >> 2) + 4 * hh;
        size_t a = ((size_t)b * 256 + c) * 2048 + t0 + q;
        out[a] = pacc[nn][mi][r] * inv + x[a];
      }
    }
  }
}

// ---------------------------------------------------------------------------
extern "C" void kernel_launch(void* const* d_in, const int* in_sizes, int n_in,
                              void* d_out, int out_size, void* d_ws, size_t ws_size,
                              hipStream_t stream) {
  const float* x  = (const float*)d_in[0];
  const float* Wq = (const float*)d_in[1];
  const float* bq = (const float*)d_in[2];
  const float* Wk = (const float*)d_in[3];
  const float* bk = (const float*)d_in[4];
  const float* Wv = (const float*)d_in[5];
  const float* bv = (const float*)d_in[6];
  char* ws = (char*)d_ws;

  pack_kernel<<<320, 256, 0, stream>>>(Wq, bq, Wk, bk, Wv, bv, ws);
  proj_kernel<<<dim3(32, 16), 256, 0, stream>>>(x, ws);
  attn_kernel<<<512, 256, 0, stream>>>(x, ws, (float*)d_out);
}

// Round 6
// 176.237 us; speedup vs baseline: 2.2692x; 2.2692x over previous
//
#include <hip/hip_runtime.h>
#include <math.h>

typedef __attribute__((ext_vector_type(8)))  short          short8;
typedef __attribute__((ext_vector_type(8)))  unsigned short ushort8;
typedef __attribute__((ext_vector_type(8)))  _Float16       half8;
typedef __attribute__((ext_vector_type(16))) float          f32x16;

#define Bb 16
#define Cc 256
#define Tt 2048

// ---- workspace layout (bytes) ----
#define WH_OFF    0u                         // ushort [320][256] bf16-hi of W
#define WL_OFF    163840u                    // ushort [320][256] bf16-lo of W
#define BALL_OFF  327680u                    // fp32 [320]
#define QTF_OFF   328960u                    // ushort [16][2048][32] fp16 bits, [t][c]
#define KTF_OFF   (QTF_OFF + 2097152u)
#define VBF_OFF   (KTF_OFF + 2097152u)       // ushort [16][256][2048] bf16 bits, [c][t]

__device__ __forceinline__ unsigned short f2bf(float f) {
  union { float f; unsigned u; } v; v.f = f;
  unsigned r = v.u + 0x7fffu + ((v.u >> 16) & 1u);   // RNE
  return (unsigned short)(r >> 16);
}
__device__ __forceinline__ float bf2f(unsigned short h) {
  union { unsigned u; float f; } v; v.u = ((unsigned)h) << 16;
  return v.f;
}
__device__ __forceinline__ unsigned short f2h(float f) {
  union { _Float16 h; unsigned short u; } v; v.h = (_Float16)f;
  return v.u;
}

// ---------------------------------------------------------------------------
// pack: W -> bf16 hi/lo planes [320][256] (+ bias fp32[320]).
// ---------------------------------------------------------------------------
__global__ __launch_bounds__(256) void pack_kernel(
    const float* __restrict__ Wq, const float* __restrict__ bq,
    const float* __restrict__ Wk, const float* __restrict__ bk,
    const float* __restrict__ Wv, const float* __restrict__ bv,
    char* ws) {
  unsigned short* WH = (unsigned short*)(ws + WH_OFF);
  unsigned short* WL = (unsigned short*)(ws + WL_OFF);
  float* ball = (float*)(ws + BALL_OFF);
  int o = blockIdx.x, c = threadIdx.x;
  float v;
  if (o < 32)      v = Wq[o * 256 + c];
  else if (o < 64) v = Wk[(o - 32) * 256 + c];
  else             v = Wv[(o - 64) * 256 + c];
  unsigned short hb = f2bf(v);
  WH[o * 256 + c] = hb;
  WL[o * 256 + c] = f2bf(v - bf2f(hb));
  if (c == 0) ball[o] = (o < 32) ? bq[o] : (o < 64 ? bk[o - 32] : bv[o - 64]);
}

// ---------------------------------------------------------------------------
// proj (MFMA): as round 3/4; Q/K epilogue -> single fp16 plane, V -> bf16.
// ---------------------------------------------------------------------------
__global__ __launch_bounds__(256, 2) void proj_kernel(
    const float* __restrict__ x, char* ws) {
  __shared__ __align__(16) float xs[128 * 64];
  __shared__ __align__(16) unsigned short xth[64 * 136];
  __shared__ __align__(16) unsigned short xtl[64 * 136];

  const unsigned short* WH = (const unsigned short*)(ws + WH_OFF);
  const unsigned short* WL = (const unsigned short*)(ws + WL_OFF);
  const float* ball = (const float*)(ws + BALL_OFF);
  unsigned short* Qtf = (unsigned short*)(ws + QTF_OFF);
  unsigned short* Ktf = (unsigned short*)(ws + KTF_OFF);
  unsigned short* Vbf = (unsigned short*)(ws + VBF_OFF);

  const int b   = blockIdx.y;
  const int t0  = blockIdx.x * 64;
  const int tid = threadIdx.x;
  const int w    = tid >> 6;
  const int lane = tid & 63;
  const int m    = lane & 31;
  const int hh   = lane >> 5;

  const float* xb = x + ((size_t)b * 256) * 2048 + t0;

  f32x16 qkacc;
  f32x16 vacc[4];
  #pragma unroll
  for (int r = 0; r < 16; ++r) qkacc[r] = 0.f;
  #pragma unroll
  for (int j = 0; j < 4; ++j)
    #pragma unroll
    for (int r = 0; r < 16; ++r) vacc[j][r] = 0.f;

  #pragma unroll
  for (int r = 0; r < 8; ++r) {
    int idx = r * 256 + tid;
    int c = idx >> 4, f = idx & 15;
    *(float4*)&xs[c * 64 + 4 * f] = *(const float4*)&xb[(size_t)c * 2048 + 4 * f];
  }
  __syncthreads();

  const int tt = w & 1;
  const int qo = 32 * (w >> 1);

  #pragma unroll
  for (int half = 0; half < 2; ++half) {
    {
      const int t = lane;
      const int cq = w * 32;
      #pragma unroll
      for (int g = 0; g < 4; ++g) {
        ushort8 h8, l8;
        #pragma unroll
        for (int j = 0; j < 8; ++j) {
          float v = xs[(cq + g * 8 + j) * 64 + t];
          unsigned short hb = f2bf(v);
          h8[j] = hb;
          l8[j] = f2bf(v - bf2f(hb));
        }
        *(ushort8*)&xth[t * 136 + cq + g * 8] = h8;
        *(ushort8*)&xtl[t * 136 + cq + g * 8] = l8;
      }
    }
    __syncthreads();

    float4 pre[8];
    if (half == 0) {
      #pragma unroll
      for (int r = 0; r < 8; ++r) {
        int idx = r * 256 + tid;
        int c = idx >> 4, f = idx & 15;
        pre[r] = *(const float4*)&xb[(size_t)(128 + c) * 2048 + 4 * f];
      }
    }

    #pragma unroll
    for (int kk = 0; kk < 8; ++kk) {
      const int kl = kk * 16 + 8 * hh;
      const int kg = half * 128 + kl;
      short8 bh = *(const short8*)&xth[(32 * tt + m) * 136 + kl];
      short8 bl = *(const short8*)&xtl[(32 * tt + m) * 136 + kl];
      short8 ah = *(const short8*)&WH[(size_t)(qo + m) * 256 + kg];
      short8 al = *(const short8*)&WL[(size_t)(qo + m) * 256 + kg];
      qkacc = __builtin_amdgcn_mfma_f32_32x32x16_bf16(ah, bh, qkacc, 0, 0, 0);
      qkacc = __builtin_amdgcn_mfma_f32_32x32x16_bf16(ah, bl, qkacc, 0, 0, 0);
      qkacc = __builtin_amdgcn_mfma_f32_32x32x16_bf16(al, bh, qkacc, 0, 0, 0);
      #pragma unroll
      for (int j = 0; j < 4; ++j) {
        short8 av = *(const short8*)&WH[(size_t)(64 + 32 * (2 * j + (w >> 1)) + m) * 256 + kg];
        vacc[j] = __builtin_amdgcn_mfma_f32_32x32x16_bf16(av, bh, vacc[j], 0, 0, 0);
      }
    }

    if (half == 0) {
      #pragma unroll
      for (int r = 0; r < 8; ++r) {
        int idx = r * 256 + tid;
        int c = idx >> 4, f = idx & 15;
        *(float4*)&xs[c * 64 + 4 * f] = pre[r];
      }
      __syncthreads();
    }
  }

  // Q/K epilogue: single fp16 plane
  {
    unsigned short* pt = (w < 2) ? Qtf : Ktf;
    const int tcol = t0 + 32 * tt + m;
    #pragma unroll
    for (int r = 0; r < 16; ++r) {
      int orow = (r & 3) + 8 * (r >> 2) + 4 * hh;
      float v = qkacc[r] + ball[qo + orow];
      pt[((size_t)b * 2048 + tcol) * 32 + orow] = f2h(v);
    }
  }
  // V epilogue: bf16 [c][t]
  #pragma unroll
  for (int j = 0; j < 4; ++j) {
    const int vob = 64 + 32 * (2 * j + (w >> 1));
    #pragma unroll
    for (int r = 0; r < 16; ++r) {
      int orow = (r & 3) + 8 * (r >> 2) + 4 * hh;
      int o = vob + orow;
      float v = vacc[j][r] + ball[o];
      Vbf[((size_t)b * 256 + (o - 64)) * 2048 + t0 + 32 * tt + m] = f2bf(v);
    }
  }
}

// ---------------------------------------------------------------------------
// attn v4: round-5 dataflow, but ALL buffers statically named (manual x2
// unroll) so nothing spills: even iter -> VsA/PsA/kA, odd -> VsB/PsB/kB.
// 1 barrier per s-tile: land V(i) + QK(i)+exp->Ps(i) | sync | PV(i).
// Prefetch V/K(i+1) into plain VGPRs right after the land (no barrier drain).
// LDS exactly 80 KB -> 2 blocks/CU; sums/invs alias PsA/PsB after the loop.
// ---------------------------------------------------------------------------
#define ATTN_ITER(VS, PS, KC0, KC1, KN0, KN1, SBN, GUARD)                       \
  {                                                                             \
    _Pragma("unroll")                                                           \
    for (int r = 0; r < 8; ++r) {                                               \
      int c = r * 32 + vc;                                                      \
      *(ushort8*)&VS[c * 64 + (((vk + c) & 7) << 3)] = vpre[r];                 \
    }                                                                           \
    if (GUARD) {                                                                \
      KN0 = *(const half8*)&Kt[((size_t)b * 2048 + (SBN) + 32 * u + m) * 32 + 8 * hh];      \
      KN1 = *(const half8*)&Kt[((size_t)b * 2048 + (SBN) + 32 * u + m) * 32 + 16 + 8 * hh]; \
      _Pragma("unroll")                                                         \
      for (int r = 0; r < 8; ++r) {                                             \
        int c = r * 32 + vc;                                                    \
        vpre[r] = *(const ushort8*)&Vg[(size_t)c * 2048 + (SBN) + vk * 8];      \
      }                                                                         \
    }                                                                           \
    {                                                                           \
      f32x16 qacc;                                                              \
      _Pragma("unroll")                                                         \
      for (int r = 0; r < 16; ++r) qacc[r] = 0.f;                               \
      qacc = __builtin_amdgcn_mfma_f32_32x32x16_f16(qf0, KC0, qacc, 0, 0, 0);   \
      qacc = __builtin_amdgcn_mfma_f32_32x32x16_f16(qf1, KC1, qacc, 0, 0, 0);   \
      _Pragma("unroll")                                                         \
      for (int r = 0; r < 16; ++r) {                                            \
        float e = __expf(qacc[r]);                                              \
        unsigned short hb = f2bf(e);                                            \
        sacc[r] += bf2f(hb);                                                    \
        int qq = 32 * n + (r & 3) + 8 * (r >> 2) + 4 * hh;                      \
        PS[qq * 64 + (((scu + qq) & 7) << 3) + sco] = hb;                       \
      }                                                                         \
    }                                                                           \
    __syncthreads();                                                            \
    _Pragma("unroll")                                                           \
    for (int ks = 0; ks < 4; ++ks) {                                            \
      const int uu = 2 * ks + hh;                                               \
      short8 pp0 = *(const short8*)&PS[m * 64 + (((uu + m) & 7) << 3)];         \
      short8 pp1 = *(const short8*)&PS[(32 + m) * 64 + (((uu + m) & 7) << 3)];  \
      short8 vv0 = *(const short8*)&VS[c0 * 64 + (((uu + c0) & 7) << 3)];       \
      short8 vv1 = *(const short8*)&VS[c1 * 64 + (((uu + c1) & 7) << 3)];       \
      pacc[0][0] = __builtin_amdgcn_mfma_f32_32x32x16_bf16(vv0, pp0, pacc[0][0], 0, 0, 0); \
      pacc[0][1] = __builtin_amdgcn_mfma_f32_32x32x16_bf16(vv1, pp0, pacc[0][1], 0, 0, 0); \
      pacc[1][0] = __builtin_amdgcn_mfma_f32_32x32x16_bf16(vv0, pp1, pacc[1][0], 0, 0, 0); \
      pacc[1][1] = __builtin_amdgcn_mfma_f32_32x32x16_bf16(vv1, pp1, pacc[1][1], 0, 0, 0); \
    }                                                                           \
  }

__global__ __launch_bounds__(256, 2) void attn_kernel(
    const float* __restrict__ x, const char* __restrict__ ws,
    float* __restrict__ out) {
  __shared__ __align__(16) unsigned short VsA[256 * 64];   // 32 KB
  __shared__ __align__(16) unsigned short VsB[256 * 64];   // 32 KB
  __shared__ __align__(16) unsigned short PsA[64 * 64];    // 8 KB
  __shared__ __align__(16) unsigned short PsB[64 * 64];    // 8 KB  (total 80 KB)

  const unsigned short* Qt = (const unsigned short*)(ws + QTF_OFF);
  const unsigned short* Kt = (const unsigned short*)(ws + KTF_OFF);

  const int id = blockIdx.x;
  const int b  = ((id & 7) << 1) | ((id >> 3) & 1);   // 2 batches per XCD
  const int qt = id >> 4;
  const int t0 = qt * 64;
  const int tid  = threadIdx.x;
  const int w    = tid >> 6;
  const int lane = tid & 63;
  const int m    = lane & 31;
  const int hh   = lane >> 5;
  const int n    = w >> 1;       // q-tile for QK
  const int u    = w & 1;        // s-tile for QK
  const int vk   = tid & 7, vc = tid >> 3;
  const int c0   = 32 * w + m, c1 = 32 * (w + 4) + m;
  const int sc   = 32 * u + m, scu = sc >> 3, sco = sc & 7;

  const unsigned short* Vg =
      (const unsigned short*)(ws + VBF_OFF) + (size_t)b * 256 * 2048;

  // persistent Q frags; K frags tile 0; V tile 0 into vpre
  half8 qf0 = *(const half8*)&Qt[((size_t)b * 2048 + t0 + 32 * n + m) * 32 + 8 * hh];
  half8 qf1 = *(const half8*)&Qt[((size_t)b * 2048 + t0 + 32 * n + m) * 32 + 16 + 8 * hh];
  half8 ka0 = *(const half8*)&Kt[((size_t)b * 2048 + 32 * u + m) * 32 + 8 * hh];
  half8 ka1 = *(const half8*)&Kt[((size_t)b * 2048 + 32 * u + m) * 32 + 16 + 8 * hh];
  half8 kb0 = ka0, kb1 = ka1;
  ushort8 vpre[8];
  #pragma unroll
  for (int r = 0; r < 8; ++r) {
    int c = r * 32 + vc;
    vpre[r] = *(const ushort8*)&Vg[(size_t)c * 2048 + vk * 8];
  }

  f32x16 pacc[2][2];
  #pragma unroll
  for (int a = 0; a < 2; ++a)
    #pragma unroll
    for (int d = 0; d < 2; ++d)
      #pragma unroll
      for (int r = 0; r < 16; ++r) pacc[a][d][r] = 0.f;
  float sacc[16];
  #pragma unroll
  for (int r = 0; r < 16; ++r) sacc[r] = 0.f;

  for (int j = 0; j < 16; ++j) {
    const int sb1 = j * 128 + 64;
    const int sb2 = j * 128 + 128;
    ATTN_ITER(VsA, PsA, ka0, ka1, kb0, kb1, sb1, true)        // s-tile 2j
    ATTN_ITER(VsB, PsB, kb0, kb1, ka0, ka1, sb2, (j < 15))    // s-tile 2j+1
  }

  // ---- row sums (alias retired Ps buffers) ----
  float* sums = (float*)PsA;   // [64][2]
  float* invs = (float*)PsB;   // [64]
  #pragma unroll
  for (int r = 0; r < 16; ++r) {
    float v = sacc[r];
    #pragma unroll
    for (int off = 1; off < 32; off <<= 1) v += __shfl_xor(v, off, 64);
    if (m == 0) sums[(32 * n + (r & 3) + 8 * (r >> 2) + 4 * hh) * 2 + u] = v;
  }
  __syncthreads();
  if (tid < 64) invs[tid] = 1.0f / (sums[tid * 2] + sums[tid * 2 + 1]);
  __syncthreads();

  // ---- epilogue: out = pacc/sum + x, coalesced along t (col = q) ----
  const float inv0 = invs[m], inv1 = invs[32 + m];
  #pragma unroll
  for (int nn = 0; nn < 2; ++nn) {
    const float inv = nn ? inv1 : inv0;
    const int q = 32 * nn + m;
    #pragma unroll
    for (int mi = 0; mi < 2; ++mi) {
      const int cbase = 32 * (w + 4 * mi);
      #pragma unroll
      for (int r = 0; r < 16; ++r) {
        int c = cbase + (r & 3) + 8 * (r >> 2) + 4 * hh;
        size_t a = ((size_t)b * 256 + c) * 2048 + t0 + q;
        out[a] = pacc[nn][mi][r] * inv + x[a];
      }
    }
  }
}

// ---------------------------------------------------------------------------
extern "C" void kernel_launch(void* const* d_in, const int* in_sizes, int n_in,
                              void* d_out, int out_size, void* d_ws, size_t ws_size,
                              hipStream_t stream) {
  const float* x  = (const float*)d_in[0];
  const float* Wq = (const float*)d_in[1];
  const float* bq = (const float*)d_in[2];
  const float* Wk = (const float*)d_in[3];
  const float* bk = (const float*)d_in[4];
  const float* Wv = (const float*)d_in[5];
  const float* bv = (const float*)d_in[6];
  char* ws = (char*)d_ws;

  pack_kernel<<<320, 256, 0, stream>>>(Wq, bq, Wk, bk, Wv, bv, ws);
  proj_kernel<<<dim3(32, 16), 256, 0, stream>>>(x, ws);
  attn_kernel<<<512, 256, 0, stream>>>(x, ws, (float*)d_out);
}